// Round 1
// baseline (1645.721 us; speedup 1.0000x reference)
//
#include <hip/hip_runtime.h>

// Problem constants (B=2, C=64, H=W=256, G=8, K=3)
constexpr int H = 256, W = 256;
constexpr size_t HW = (size_t)H * W;   // 65536
constexpr int B = 2;

// ---------------------------------------------------------------------------
// Generic direct 3x3 SAME conv, NCHW.
//   input = concat(xa[CIN_A], xb[CIN_B]) along channels
//   y[b,co,h,w] = bias[co] + sum_{ci,dy,dx} wt[co,ci,dy,dx]*x[b,ci,h+dy-1,w+dx-1]
//   optional ReLU, optional residual add (resid has Cout channels layout)
// Block: 256 threads = 16x16 pixel tile, each thread: 1 pixel x 16 out chans.
// ---------------------------------------------------------------------------
template<int CIN_A, int CIN_B, bool RELU, bool RESID>
__global__ __launch_bounds__(256) void conv3x3_k(
    const float* __restrict__ xa, const float* __restrict__ xb,
    const float* __restrict__ wt, const float* __restrict__ bias,
    const float* __restrict__ resid, float* __restrict__ y, int Cout)
{
    constexpr int CIN = CIN_A + CIN_B;
    constexpr int CC  = 4;    // input-channel chunk staged in LDS
    constexpr int COT = 16;   // output channels per block

    __shared__ float smem[CC * 324];   // CC channels of 18x18 halo tile

    const int tid = threadIdx.x;
    const int t  = blockIdx.x;              // 0..255 tile id
    const int ox = (t & 15) * 16;
    const int oy = (t >> 4) * 16;
    const int tx = tid & 15;
    const int ty = tid >> 4;
    const int wcol = ox + tx;
    const int h    = oy + ty;
    const int cobase = blockIdx.y * COT;
    const int bi     = blockIdx.z;

    float acc[COT];
#pragma unroll
    for (int i = 0; i < COT; ++i) acc[i] = bias[cobase + i];

    for (int cib = 0; cib < CIN; cib += CC) {
        const float* src;
        if (cib < CIN_A) src = xa + ((size_t)(bi * CIN_A + cib)) * HW;
        else             src = xb + ((size_t)(bi * CIN_B + (cib - CIN_A))) * HW;

        __syncthreads();
        // stage CC x 18 x 18 (zero-padded SAME halo)
#pragma unroll
        for (int e = 0; e < CC * 324; e += 256) {
            int idx = e + tid;
            if (idx < CC * 324) {
                int cc = idx / 324;
                int rem = idx - cc * 324;
                int r  = rem / 18;
                int cl = rem - r * 18;
                int gh = oy + r - 1, gw = ox + cl - 1;
                float v = 0.f;
                if (gh >= 0 && gh < H && gw >= 0 && gw < W)
                    v = src[(size_t)cc * HW + (size_t)gh * W + gw];
                smem[idx] = v;
            }
        }
        __syncthreads();

#pragma unroll
        for (int cc = 0; cc < CC; ++cc) {
            float v[9];
#pragma unroll
            for (int dy = 0; dy < 3; ++dy)
#pragma unroll
                for (int dx = 0; dx < 3; ++dx)
                    v[dy * 3 + dx] = smem[cc * 324 + (ty + dy) * 18 + (tx + dx)];

            // weights: block-uniform index -> expect s_load (SGPR operands)
            const float* wp = wt + ((size_t)cobase * CIN + (size_t)(cib + cc)) * 9;
#pragma unroll
            for (int co = 0; co < COT; ++co) {
                const float* wq = wp + (size_t)co * CIN * 9;
                float a = acc[co];
#pragma unroll
                for (int k = 0; k < 9; ++k) a = fmaf(wq[k], v[k], a);
                acc[co] = a;
            }
        }
    }

    const size_t ob = ((size_t)(bi * Cout + cobase)) * HW + (size_t)h * W + wcol;
    const size_t rb = ((size_t)(bi * 64 + cobase)) * HW + (size_t)h * W + wcol;
#pragma unroll
    for (int co = 0; co < COT; ++co) {
        float vv = acc[co];
        if (RELU) vv = fmaxf(vv, 0.f);
        if (RESID) vv += resid[rb + (size_t)co * HW];
        y[ob + (size_t)co * HW] = vv;
    }
}

// ---------------------------------------------------------------------------
// Deformable conv (G=8 groups, Cg=8, K=3x3), bilinear sampling w/ per-corner
// zero-pad masking, then the 8x72 per-group einsum.
// Block: 256 threads = 16x16 pixel tile; grid: (tiles, G, B).
// ---------------------------------------------------------------------------
__global__ __launch_bounds__(256) void deform_k(
    const float* __restrict__ ref, const float* __restrict__ doff,
    const float* __restrict__ wdef, const float* __restrict__ bdef,
    float* __restrict__ out)
{
    const int tid = threadIdx.x;
    const int t  = blockIdx.x;
    const int ox = (t & 15) * 16;
    const int oy = (t >> 4) * 16;
    const int tx = tid & 15;
    const int ty = tid >> 4;
    const int wcol = ox + tx;
    const int h    = oy + ty;
    const int g  = blockIdx.y;
    const int bi = blockIdx.z;

    const float* refb = ref  + ((size_t)(bi * 64 + g * 8)) * HW;
    const float* offb = doff + ((size_t)(bi * 144 + g * 18)) * HW + (size_t)h * W + wcol;

    float acc[8];
#pragma unroll
    for (int o = 0; o < 8; ++o) acc[o] = bdef[g * 8 + o];

#pragma unroll
    for (int k = 0; k < 9; ++k) {
        const float dy = offb[(size_t)(2 * k) * HW];
        const float dx = offb[(size_t)(2 * k + 1) * HW];
        const float py = dy + (float)(h + k / 3 - 1);
        const float px = dx + (float)(wcol + k % 3 - 1);
        const float fy = floorf(py), fx = floorf(px);
        const int y0 = (int)fy, x0 = (int)fx;
        const float ly = py - fy, lx = px - fx;
        const int y1 = y0 + 1, x1 = x0 + 1;
        const bool vy0 = (y0 >= 0) && (y0 < H);
        const bool vy1 = (y1 >= 0) && (y1 < H);
        const bool vx0 = (x0 >= 0) && (x0 < W);
        const bool vx1 = (x1 >= 0) && (x1 < W);
        const int cy0 = min(max(y0, 0), H - 1), cy1 = min(max(y1, 0), H - 1);
        const int cx0 = min(max(x0, 0), W - 1), cx1 = min(max(x1, 0), W - 1);
        const int i00 = cy0 * W + cx0, i01 = cy0 * W + cx1;
        const int i10 = cy1 * W + cx0, i11 = cy1 * W + cx1;
        float w00 = (1.f - ly) * (1.f - lx);
        float w01 = (1.f - ly) * lx;
        float w10 = ly * (1.f - lx);
        float w11 = ly * lx;
        if (!(vy0 && vx0)) w00 = 0.f;
        if (!(vy0 && vx1)) w01 = 0.f;
        if (!(vy1 && vx0)) w10 = 0.f;
        if (!(vy1 && vx1)) w11 = 0.f;

#pragma unroll
        for (int c = 0; c < 8; ++c) {
            const float* rp = refb + (size_t)c * HW;
            const float s = w00 * rp[i00] + w01 * rp[i01]
                          + w10 * rp[i10] + w11 * rp[i11];
            // wdef[(g*8+o)*72 + c*9 + k] -- block-uniform -> s_load
            const float* wq = wdef + (size_t)(g * 8) * 72 + (size_t)c * 9 + k;
#pragma unroll
            for (int o = 0; o < 8; ++o)
                acc[o] = fmaf(wq[(size_t)o * 72], s, acc[o]);
        }
    }

    const size_t obase = ((size_t)(bi * 64 + g * 8)) * HW + (size_t)h * W + wcol;
#pragma unroll
    for (int o = 0; o < 8; ++o) out[obase + (size_t)o * HW] = acc[o];
}

// ---------------------------------------------------------------------------
extern "C" void kernel_launch(void* const* d_in, const int* in_sizes, int n_in,
                              void* d_out, int out_size, void* d_ws, size_t ws_size,
                              hipStream_t stream)
{
    const float* offset = (const float*)d_in[0];
    const float* ref    = (const float*)d_in[1];
    const float* w_off  = (const float*)d_in[2];
    const float* b_off  = (const float*)d_in[3];
    const float* w_def  = (const float*)d_in[4];
    const float* b_def  = (const float*)d_in[5];
    const float* w_r1   = (const float*)d_in[6];
    const float* b_r1   = (const float*)d_in[7];
    const float* w_r2   = (const float*)d_in[8];
    const float* b_r2   = (const float*)d_in[9];
    float* out = (float*)d_out;

    // workspace layout (floats): doff[2*144*65536] | aligned[2*64*65536] | x1[...]
    float* doff    = (float*)d_ws;
    float* aligned = doff + (size_t)B * 144 * HW;     // +18,874,368
    float* x1      = aligned + (size_t)B * 64 * HW;   // + 8,388,608
    // total: 142.6 MB of ws

    dim3 blk(256);

    // 1) deform_offsets = conv3x3(offset, w_off)   64 -> 144
    conv3x3_k<64, 0, false, false><<<dim3(256, 9, B), blk, 0, stream>>>(
        offset, nullptr, w_off, b_off, nullptr, doff, 144);

    // 2) aligned = deform_conv2d(ref, doff, w_def, b_def)
    deform_k<<<dim3(256, 8, B), blk, 0, stream>>>(ref, doff, w_def, b_def, aligned);

    // 3) x1 = relu(conv3x3(concat(ref, aligned), w_r1))   128 -> 64
    conv3x3_k<64, 64, true, false><<<dim3(256, 4, B), blk, 0, stream>>>(
        ref, aligned, w_r1, b_r1, nullptr, x1, 64);

    // 4) out = relu(conv3x3(x1, w_r2)) + aligned          64 -> 64
    conv3x3_k<64, 0, true, true><<<dim3(256, 4, B), blk, 0, stream>>>(
        x1, nullptr, w_r2, b_r2, aligned, out, 64);
}

// Round 2
// 635.142 us; speedup vs baseline: 2.5911x; 2.5911x over previous
//
#include <hip/hip_runtime.h>

typedef __attribute__((ext_vector_type(8))) short short8;
typedef __attribute__((ext_vector_type(4))) float float4v;

constexpr int HH = 256, WW = 256;
constexpr int PD = 258;                 // padded spatial dim
constexpr size_t HWsz = (size_t)HH * WW;

__device__ inline unsigned short f2bf(float f) {
    unsigned int u = __builtin_bit_cast(unsigned int, f);
    u += 0x7FFFu + ((u >> 16) & 1u);
    return (unsigned short)(u >> 16);
}
__device__ inline float bfhalf(unsigned int w, int hi) {
    return __builtin_bit_cast(float, hi ? (w & 0xFFFF0000u) : (w << 16));
}

// ---------------------------------------------------------------------------
// fp32 NCHW (64 ch) -> bf16 zero-padded NHWC [258][258][CDST], channels 0..63
// ---------------------------------------------------------------------------
template<int CDST>
__global__ __launch_bounds__(256) void nchw_to_nhwc(
    const float* __restrict__ src, unsigned short* __restrict__ dst)
{
    const int px = threadIdx.x, h = blockIdx.x, bi = blockIdx.y;
    const float* s = src + (size_t)bi * 64 * HWsz + (size_t)h * WW + px;
    unsigned short* d = dst + (((size_t)bi * PD + (h + 1)) * PD + (px + 1)) * CDST;
#pragma unroll
    for (int cg = 0; cg < 8; ++cg) {
        unsigned int w0, w1, w2, w3;
        float v[8];
#pragma unroll
        for (int j = 0; j < 8; ++j) v[j] = s[(size_t)(cg * 8 + j) * HWsz];
        w0 = f2bf(v[0]) | ((unsigned)f2bf(v[1]) << 16);
        w1 = f2bf(v[2]) | ((unsigned)f2bf(v[3]) << 16);
        w2 = f2bf(v[4]) | ((unsigned)f2bf(v[5]) << 16);
        w3 = f2bf(v[6]) | ((unsigned)f2bf(v[7]) << 16);
        uint4 pk = {w0, w1, w2, w3};
        *(uint4*)&d[cg * 8] = pk;
    }
}

// ---------------------------------------------------------------------------
// Pack conv weights (OIHW fp32) into MFMA A-frag order, bf16:
// wpk[((cot*KSTEPS + kstep)*64 + lane)*8 + j]
//   co = cot*16 + (lane&15); tap = kstep/(Cin/32);
//   ci = (kstep%(Cin/32))*32 + (lane>>4)*8 + j.  Zero-pad co >= Cout.
// ---------------------------------------------------------------------------
__global__ __launch_bounds__(256) void pack_w(
    const float* __restrict__ w, short* __restrict__ wpk,
    int Cout, int Cin, int nElems)
{
    int e = blockIdx.x * 256 + threadIdx.x;
    if (e >= nElems) return;
    int j = e & 7;
    int lane = (e >> 3) & 63;
    int ksp = 9 * (Cin / 32);
    int kstep = (e >> 9) % ksp;
    int cot = (e >> 9) / ksp;
    int tap = kstep / (Cin / 32);
    int ci = (kstep % (Cin / 32)) * 32 + (lane >> 4) * 8 + j;
    int co = cot * 16 + (lane & 15);
    float v = (co < Cout) ? w[((size_t)co * Cin + ci) * 9 + tap] : 0.f;
    wpk[e] = (short)f2bf(v);
}

// ---------------------------------------------------------------------------
// Implicit-GEMM 3x3 conv, bf16 MFMA 16x16x32.
// Block: 4 waves = 2(co)x2(px): 64 co x 128 px.  Grid: (2 xtiles, 256 rows, B*COTB).
// src: padded NHWC bf16 [B][258][258][CIN].
// MODE 0: dst_bf = NHWC [256][256][144], guard co<144 (deform offsets)
// MODE 1: dst_bf = padded NHWC [258][258][64], ReLU (x1)
// MODE 2: dst_f  = NCHW fp32 + ReLU + residual (final out)
// ---------------------------------------------------------------------------
template<int CIN, int MODE, int COTB>
__global__ __launch_bounds__(256) void conv_mfma(
    const unsigned short* __restrict__ src,
    const short* __restrict__ wpk,
    const float* __restrict__ bias,
    unsigned short* __restrict__ dst_bf,
    float* __restrict__ dst_f,
    const float* __restrict__ resid)
{
    constexpr int KSTEPS = 9 * (CIN / 32);
    constexpr int CHUNKS = CIN / 64;

    __shared__ unsigned short lds[3 * 130 * 64];   // 49,920 B, ci XOR-swizzled

    const int tid = threadIdx.x;
    const int lane = tid & 63;
    const int wv = tid >> 6;
    const int wy = wv >> 1;          // co half
    const int wx = wv & 1;           // px half
    const int quad = lane >> 4;
    const int nIdx = lane & 15;
    const int x0 = blockIdx.x * 128;
    const int h = blockIdx.y;
    const int bi = blockIdx.z / COTB;
    const int cb = blockIdx.z % COTB;
    const int coW = cb * 64 + wy * 32;

    const unsigned short* srcB = src + (size_t)bi * PD * PD * CIN;
    const short8* wbase = (const short8*)wpk;

    float4v acc[2][4];
#pragma unroll
    for (int af = 0; af < 2; ++af) {
        float4v b4;
#pragma unroll
        for (int r = 0; r < 4; ++r) {
            int co = coW + af * 16 + quad * 4 + r;
            float bv = 0.f;
            if (MODE != 0 || co < 144) bv = bias[co];
            b4[r] = bv;
        }
#pragma unroll
        for (int nt = 0; nt < 4; ++nt) acc[af][nt] = b4;
    }

    for (int ch = 0; ch < CHUNKS; ++ch) {
        __syncthreads();
        // stage 3 rows x 130 px x 64 ci (bf16), XOR-swizzle ci by px
        const unsigned short* g0 = srcB + ((size_t)h * PD + x0) * CIN + ch * 64;
#pragma unroll
        for (int r = 0; r < 3; ++r) {
            const unsigned short* grow = g0 + (size_t)r * PD * CIN;
            for (int q = tid; q < 1040; q += 256) {
                int px = q >> 3, cg = q & 7;
                uint4 v = *(const uint4*)(grow + (size_t)px * CIN + cg * 8);
                int ciSw = (cg * 8) ^ ((px & 7) << 3);
                *(uint4*)&lds[(r * 130 + px) * 64 + ciSw] = v;
            }
        }
        __syncthreads();

#pragma unroll
        for (int tap = 0; tap < 9; ++tap) {
            const int row = tap / 3, dxo = tap % 3;
#pragma unroll
            for (int s = 0; s < 2; ++s) {
                const int kstep = tap * (CIN / 32) + ch * 2 + s;
                short8 a0 = wbase[((size_t)(cb * 4 + wy * 2 + 0) * KSTEPS + kstep) * 64 + lane];
                short8 a1 = wbase[((size_t)(cb * 4 + wy * 2 + 1) * KSTEPS + kstep) * 64 + lane];
#pragma unroll
                for (int nt = 0; nt < 4; ++nt) {
                    int px = wx * 64 + nt * 16 + nIdx + dxo;
                    int ci = (s * 32 + quad * 8) ^ ((px & 7) << 3);
                    short8 b = *(const short8*)&lds[(row * 130 + px) * 64 + ci];
                    acc[0][nt] = __builtin_amdgcn_mfma_f32_16x16x32_bf16(a0, b, acc[0][nt], 0, 0, 0);
                    acc[1][nt] = __builtin_amdgcn_mfma_f32_16x16x32_bf16(a1, b, acc[1][nt], 0, 0, 0);
                }
            }
        }
    }

    // epilogue
#pragma unroll
    for (int af = 0; af < 2; ++af) {
        const int co = coW + af * 16 + quad * 4;
#pragma unroll
        for (int nt = 0; nt < 4; ++nt) {
            const int px = x0 + wx * 64 + nt * 16 + nIdx;
            float4v a = acc[af][nt];
            if (MODE == 0) {
                if (co < 144) {
                    unsigned short* d = dst_bf + (size_t)bi * HWsz * 144;
                    uint2 pk;
                    pk.x = f2bf(a[0]) | ((unsigned)f2bf(a[1]) << 16);
                    pk.y = f2bf(a[2]) | ((unsigned)f2bf(a[3]) << 16);
                    *(uint2*)&d[((size_t)h * WW + px) * 144 + co] = pk;
                }
            } else if (MODE == 1) {
                unsigned short* d = dst_bf + (size_t)bi * PD * PD * 64;
                float v0 = fmaxf(a[0], 0.f), v1 = fmaxf(a[1], 0.f);
                float v2 = fmaxf(a[2], 0.f), v3 = fmaxf(a[3], 0.f);
                uint2 pk;
                pk.x = f2bf(v0) | ((unsigned)f2bf(v1) << 16);
                pk.y = f2bf(v2) | ((unsigned)f2bf(v3) << 16);
                *(uint2*)&d[(((size_t)h + 1) * PD + (px + 1)) * 64 + co] = pk;
            } else {
                float* d = dst_f + (size_t)bi * 64 * HWsz;
                const float* rs = resid + (size_t)bi * 64 * HWsz;
#pragma unroll
                for (int r = 0; r < 4; ++r) {
                    size_t idx = (size_t)(co + r) * HWsz + (size_t)h * WW + px;
                    d[idx] = fmaxf(a[r], 0.f) + rs[idx];
                }
            }
        }
    }
}

// ---------------------------------------------------------------------------
// Deformable conv. Block = 256 px (one row), grid (256 rows, 8 g, B).
// Reads doff NHWC bf16 [256][256][144], ref from p_cat cols 0..63 (padded NHWC
// C=128); writes p_cat cols 64..127 (bf16) and aligned fp32 NCHW.
// ---------------------------------------------------------------------------
__global__ __launch_bounds__(256) void deform_k2(
    const unsigned short* __restrict__ pcat,
    const unsigned short* __restrict__ doff,
    const float* __restrict__ wdef, const float* __restrict__ bdef,
    unsigned short* __restrict__ pcat_out,
    float* __restrict__ alignedf)
{
    __shared__ float wsm2[576];    // [k][c][o]
    const int px = threadIdx.x, h = blockIdx.x, g = blockIdx.y, bi = blockIdx.z;

    for (int i = threadIdx.x; i < 576; i += 256) {
        int o = i & 7, c = (i >> 3) & 7, k = i >> 6;
        wsm2[i] = wdef[(size_t)g * 576 + o * 72 + c * 9 + k];
    }
    __syncthreads();

    const unsigned int* dp = (const unsigned int*)(
        doff + (((size_t)bi * HWsz) + (size_t)h * WW + px) * 144 + g * 18);
    unsigned int dw[9];
#pragma unroll
    for (int j = 0; j < 9; ++j) dw[j] = dp[j];

    float acc[8];
#pragma unroll
    for (int o = 0; o < 8; ++o) acc[o] = bdef[g * 8 + o];

    const unsigned short* rb = pcat + (size_t)bi * PD * PD * 128 + g * 8;

#pragma unroll
    for (int k = 0; k < 9; ++k) {
        float dy = bfhalf(dw[k], 0);
        float dx = bfhalf(dw[k], 1);
        float py = dy + (float)(h + k / 3 - 1);
        float pxs = dx + (float)(px + k % 3 - 1);
        float fy = floorf(py), fx = floorf(pxs);
        int y0 = (int)fy, x0i = (int)fx;
        float ly = py - fy, lx = pxs - fx;
        int y1 = y0 + 1, x1i = x0i + 1;
        bool vy0 = (y0 >= 0) & (y0 < HH), vy1 = (y1 >= 0) & (y1 < HH);
        bool vx0 = (x0i >= 0) & (x0i < WW), vx1 = (x1i >= 0) & (x1i < WW);
        int cy0 = min(max(y0, 0), HH - 1), cy1 = min(max(y1, 0), HH - 1);
        int cx0 = min(max(x0i, 0), WW - 1), cx1 = min(max(x1i, 0), WW - 1);
        float w00 = (1.f - ly) * (1.f - lx), w01 = (1.f - ly) * lx;
        float w10 = ly * (1.f - lx), w11 = ly * lx;
        if (!(vy0 && vx0)) w00 = 0.f;
        if (!(vy0 && vx1)) w01 = 0.f;
        if (!(vy1 && vx0)) w10 = 0.f;
        if (!(vy1 && vx1)) w11 = 0.f;

        uint4 q00 = *(const uint4*)(rb + ((size_t)(cy0 + 1) * PD + (cx0 + 1)) * 128);
        uint4 q01 = *(const uint4*)(rb + ((size_t)(cy0 + 1) * PD + (cx1 + 1)) * 128);
        uint4 q10 = *(const uint4*)(rb + ((size_t)(cy1 + 1) * PD + (cx0 + 1)) * 128);
        uint4 q11 = *(const uint4*)(rb + ((size_t)(cy1 + 1) * PD + (cx1 + 1)) * 128);
        union U { uint4 v; unsigned int a[4]; };
        U u00{q00}, u01{q01}, u10{q10}, u11{q11};

#pragma unroll
        for (int cw = 0; cw < 4; ++cw) {
#pragma unroll
            for (int hl = 0; hl < 2; ++hl) {
                int c = cw * 2 + hl;
                float sv = w00 * bfhalf(u00.a[cw], hl) + w01 * bfhalf(u01.a[cw], hl)
                         + w10 * bfhalf(u10.a[cw], hl) + w11 * bfhalf(u11.a[cw], hl);
                const float* wp = &wsm2[((k * 8) + c) * 8];
                float4v wlo = *(const float4v*)wp;
                float4v whi = *(const float4v*)(wp + 4);
                acc[0] += wlo[0] * sv; acc[1] += wlo[1] * sv;
                acc[2] += wlo[2] * sv; acc[3] += wlo[3] * sv;
                acc[4] += whi[0] * sv; acc[5] += whi[1] * sv;
                acc[6] += whi[2] * sv; acc[7] += whi[3] * sv;
            }
        }
    }

    float* af = alignedf + ((size_t)(bi * 64 + g * 8)) * HWsz + (size_t)h * WW + px;
#pragma unroll
    for (int o = 0; o < 8; ++o) af[(size_t)o * HWsz] = acc[o];

    unsigned short* po = pcat_out + (((size_t)bi * PD + (h + 1)) * PD + (px + 1)) * 128 + 64 + g * 8;
    uint4 pk;
    pk.x = f2bf(acc[0]) | ((unsigned)f2bf(acc[1]) << 16);
    pk.y = f2bf(acc[2]) | ((unsigned)f2bf(acc[3]) << 16);
    pk.z = f2bf(acc[4]) | ((unsigned)f2bf(acc[5]) << 16);
    pk.w = f2bf(acc[6]) | ((unsigned)f2bf(acc[7]) << 16);
    *(uint4*)po = pk;
}

// ---------------------------------------------------------------------------
extern "C" void kernel_launch(void* const* d_in, const int* in_sizes, int n_in,
                              void* d_out, int out_size, void* d_ws, size_t ws_size,
                              hipStream_t stream)
{
    const float* offset = (const float*)d_in[0];
    const float* ref    = (const float*)d_in[1];
    const float* w_off  = (const float*)d_in[2];
    const float* b_off  = (const float*)d_in[3];
    const float* w_def  = (const float*)d_in[4];
    const float* b_def  = (const float*)d_in[5];
    const float* w_r1   = (const float*)d_in[6];
    const float* b_r1   = (const float*)d_in[7];
    const float* w_r2   = (const float*)d_in[8];
    const float* b_r2   = (const float*)d_in[9];
    float* out = (float*)d_out;

    // workspace layout (ushort elems unless noted)
    unsigned short* p_off = (unsigned short*)d_ws;          // 2*258*258*64   = 8,520,192
    unsigned short* p_cat = p_off + (size_t)8520192;        // 2*258*258*128  = 17,040,384
    unsigned short* p_x1  = p_cat + (size_t)17040384;       // 8,520,192
    unsigned short* doff  = p_x1 + (size_t)8520192;         // 2*256*256*144  = 18,874,368
    float* alignedf = (float*)(doff + (size_t)18874368);    // 8,388,608 floats
    short* wpk1  = (short*)(alignedf + (size_t)8388608);    // 110,592
    short* wpkr1 = wpk1 + 110592;                           // 73,728
    short* wpkr2 = wpkr1 + 73728;                           // 36,864
    // total ~133.4 MB

    // zero the three padded NHWC buffers (borders must be 0 every call)
    hipMemsetAsync(d_ws, 0, (size_t)(8520192 + 17040384 + 8520192) * 2, stream);

    pack_w<<<dim3((110592 + 255) / 256), 256, 0, stream>>>(w_off, wpk1, 144, 64, 110592);
    pack_w<<<dim3((73728 + 255) / 256), 256, 0, stream>>>(w_r1, wpkr1, 64, 128, 73728);
    pack_w<<<dim3((36864 + 255) / 256), 256, 0, stream>>>(w_r2, wpkr2, 64, 64, 36864);

    nchw_to_nhwc<64><<<dim3(256, 2), 256, 0, stream>>>(offset, p_off);
    nchw_to_nhwc<128><<<dim3(256, 2), 256, 0, stream>>>(ref, p_cat);

    // conv1: 64 -> 144 (padded 192, COTB=3)
    conv_mfma<64, 0, 3><<<dim3(2, 256, 6), 256, 0, stream>>>(
        p_off, wpk1, b_off, doff, nullptr, nullptr);

    // deform
    deform_k2<<<dim3(256, 8, 2), 256, 0, stream>>>(
        p_cat, doff, w_def, b_def, p_cat, alignedf);

    // r1: 128 -> 64, ReLU
    conv_mfma<128, 1, 1><<<dim3(2, 256, 2), 256, 0, stream>>>(
        p_cat, wpkr1, b_r1, p_x1, nullptr, nullptr);

    // r2: 64 -> 64, ReLU + residual
    conv_mfma<64, 2, 1><<<dim3(2, 256, 2), 256, 0, stream>>>(
        p_x1, wpkr2, b_r2, nullptr, out, alignedf);
}

// Round 3
// 372.403 us; speedup vs baseline: 4.4192x; 1.7055x over previous
//
#include <hip/hip_runtime.h>

typedef __attribute__((ext_vector_type(8))) short short8;
typedef __attribute__((ext_vector_type(4))) float float4v;

constexpr int HH = 256, WW = 256;
constexpr int PD = 258;                 // padded spatial dim
constexpr size_t HWsz = (size_t)HH * WW;

__device__ inline unsigned short f2bf(float f) {
    unsigned int u = __builtin_bit_cast(unsigned int, f);
    u += 0x7FFFu + ((u >> 16) & 1u);
    return (unsigned short)(u >> 16);
}
__device__ inline float bfhalf(unsigned int w, int hi) {
    return __builtin_bit_cast(float, hi ? (w & 0xFFFF0000u) : (w << 16));
}

// ---------------------------------------------------------------------------
// fp32 NCHW (64 ch) -> bf16 zero-padded NHWC [258][258][CDST], channels 0..63.
// If WRITE_G: also write group-major refg[b][g=cg][y][x][8ch] (unpadded).
// ---------------------------------------------------------------------------
template<int CDST, bool WRITE_G>
__global__ __launch_bounds__(256) void nchw_to_nhwc(
    const float* __restrict__ src, unsigned short* __restrict__ dst,
    unsigned short* __restrict__ dst_g)
{
    const int px = threadIdx.x, h = blockIdx.x, bi = blockIdx.y;
    const float* s = src + (size_t)bi * 64 * HWsz + (size_t)h * WW + px;
    unsigned short* d = dst + (((size_t)bi * PD + (h + 1)) * PD + (px + 1)) * CDST;
#pragma unroll
    for (int cg = 0; cg < 8; ++cg) {
        float v[8];
#pragma unroll
        for (int j = 0; j < 8; ++j) v[j] = s[(size_t)(cg * 8 + j) * HWsz];
        uint4 pk;
        pk.x = f2bf(v[0]) | ((unsigned)f2bf(v[1]) << 16);
        pk.y = f2bf(v[2]) | ((unsigned)f2bf(v[3]) << 16);
        pk.z = f2bf(v[4]) | ((unsigned)f2bf(v[5]) << 16);
        pk.w = f2bf(v[6]) | ((unsigned)f2bf(v[7]) << 16);
        *(uint4*)&d[cg * 8] = pk;
        if (WRITE_G) {
            unsigned short* dg = dst_g +
                (((size_t)(bi * 8 + cg) * HWsz) + (size_t)h * WW + px) * 8;
            *(uint4*)dg = pk;
        }
    }
}

// ---------------------------------------------------------------------------
// Pack conv weights (OIHW fp32) into MFMA A-frag order, bf16.
// ---------------------------------------------------------------------------
__global__ __launch_bounds__(256) void pack_w(
    const float* __restrict__ w, short* __restrict__ wpk,
    int Cout, int Cin, int nElems)
{
    int e = blockIdx.x * 256 + threadIdx.x;
    if (e >= nElems) return;
    int j = e & 7;
    int lane = (e >> 3) & 63;
    int ksp = 9 * (Cin / 32);
    int kstep = (e >> 9) % ksp;
    int cot = (e >> 9) / ksp;
    int tap = kstep / (Cin / 32);
    int ci = (kstep % (Cin / 32)) * 32 + (lane >> 4) * 8 + j;
    int co = cot * 16 + (lane & 15);
    float v = (co < Cout) ? w[((size_t)co * Cin + ci) * 9 + tap] : 0.f;
    wpk[e] = (short)f2bf(v);
}

// ---------------------------------------------------------------------------
// Implicit-GEMM 3x3 conv, bf16 MFMA 16x16x32.  (unchanged from R2)
// ---------------------------------------------------------------------------
template<int CIN, int MODE, int COTB>
__global__ __launch_bounds__(256) void conv_mfma(
    const unsigned short* __restrict__ src,
    const short* __restrict__ wpk,
    const float* __restrict__ bias,
    unsigned short* __restrict__ dst_bf,
    float* __restrict__ dst_f,
    const float* __restrict__ resid)
{
    constexpr int KSTEPS = 9 * (CIN / 32);
    constexpr int CHUNKS = CIN / 64;

    __shared__ unsigned short lds[3 * 130 * 64];

    const int tid = threadIdx.x;
    const int lane = tid & 63;
    const int wv = tid >> 6;
    const int wy = wv >> 1;
    const int wx = wv & 1;
    const int quad = lane >> 4;
    const int nIdx = lane & 15;
    const int x0 = blockIdx.x * 128;
    const int h = blockIdx.y;
    const int bi = blockIdx.z / COTB;
    const int cb = blockIdx.z % COTB;
    const int coW = cb * 64 + wy * 32;

    const unsigned short* srcB = src + (size_t)bi * PD * PD * CIN;
    const short8* wbase = (const short8*)wpk;

    float4v acc[2][4];
#pragma unroll
    for (int af = 0; af < 2; ++af) {
        float4v b4;
#pragma unroll
        for (int r = 0; r < 4; ++r) {
            int co = coW + af * 16 + quad * 4 + r;
            float bv = 0.f;
            if (MODE != 0 || co < 144) bv = bias[co];
            b4[r] = bv;
        }
#pragma unroll
        for (int nt = 0; nt < 4; ++nt) acc[af][nt] = b4;
    }

    for (int ch = 0; ch < CHUNKS; ++ch) {
        __syncthreads();
        const unsigned short* g0 = srcB + ((size_t)h * PD + x0) * CIN + ch * 64;
#pragma unroll
        for (int r = 0; r < 3; ++r) {
            const unsigned short* grow = g0 + (size_t)r * PD * CIN;
            for (int q = tid; q < 1040; q += 256) {
                int px = q >> 3, cg = q & 7;
                uint4 v = *(const uint4*)(grow + (size_t)px * CIN + cg * 8);
                int ciSw = (cg * 8) ^ ((px & 7) << 3);
                *(uint4*)&lds[(r * 130 + px) * 64 + ciSw] = v;
            }
        }
        __syncthreads();

#pragma unroll
        for (int tap = 0; tap < 9; ++tap) {
            const int row = tap / 3, dxo = tap % 3;
#pragma unroll
            for (int s = 0; s < 2; ++s) {
                const int kstep = tap * (CIN / 32) + ch * 2 + s;
                short8 a0 = wbase[((size_t)(cb * 4 + wy * 2 + 0) * KSTEPS + kstep) * 64 + lane];
                short8 a1 = wbase[((size_t)(cb * 4 + wy * 2 + 1) * KSTEPS + kstep) * 64 + lane];
#pragma unroll
                for (int nt = 0; nt < 4; ++nt) {
                    int px = wx * 64 + nt * 16 + nIdx + dxo;
                    int ci = (s * 32 + quad * 8) ^ ((px & 7) << 3);
                    short8 b = *(const short8*)&lds[(row * 130 + px) * 64 + ci];
                    acc[0][nt] = __builtin_amdgcn_mfma_f32_16x16x32_bf16(a0, b, acc[0][nt], 0, 0, 0);
                    acc[1][nt] = __builtin_amdgcn_mfma_f32_16x16x32_bf16(a1, b, acc[1][nt], 0, 0, 0);
                }
            }
        }
    }

#pragma unroll
    for (int af = 0; af < 2; ++af) {
        const int co = coW + af * 16 + quad * 4;
#pragma unroll
        for (int nt = 0; nt < 4; ++nt) {
            const int px = x0 + wx * 64 + nt * 16 + nIdx;
            float4v a = acc[af][nt];
            if (MODE == 0) {
                if (co < 144) {
                    unsigned short* d = dst_bf + (size_t)bi * HWsz * 144;
                    uint2 pk;
                    pk.x = f2bf(a[0]) | ((unsigned)f2bf(a[1]) << 16);
                    pk.y = f2bf(a[2]) | ((unsigned)f2bf(a[3]) << 16);
                    *(uint2*)&d[((size_t)h * WW + px) * 144 + co] = pk;
                }
            } else if (MODE == 1) {
                unsigned short* d = dst_bf + (size_t)bi * PD * PD * 64;
                float v0 = fmaxf(a[0], 0.f), v1 = fmaxf(a[1], 0.f);
                float v2 = fmaxf(a[2], 0.f), v3 = fmaxf(a[3], 0.f);
                uint2 pk;
                pk.x = f2bf(v0) | ((unsigned)f2bf(v1) << 16);
                pk.y = f2bf(v2) | ((unsigned)f2bf(v3) << 16);
                *(uint2*)&d[(((size_t)h + 1) * PD + (px + 1)) * 64 + co] = pk;
            } else {
                float* d = dst_f + (size_t)bi * 64 * HWsz;
                const float* rs = resid + (size_t)bi * 64 * HWsz;
#pragma unroll
                for (int r = 0; r < 4; ++r) {
                    size_t idx = (size_t)(co + r) * HWsz + (size_t)h * WW + px;
                    d[idx] = fmaxf(a[r], 0.f) + rs[idx];
                }
            }
        }
    }
}

// ---------------------------------------------------------------------------
// Deformable conv v3: group-major ref layout + XCD row-band swizzle.
// Block = 256 px (one row, one group).  Grid = 4096 linear blocks:
//   xcd = L&7 -> row band [xcd*32, xcd*32+32); g varies fastest within band.
// refg: [b][g][256][256][8ch] bf16 (16 B pixel-group records).
// ---------------------------------------------------------------------------
__global__ __launch_bounds__(256) void deform_k3(
    const unsigned short* __restrict__ refg,
    const unsigned short* __restrict__ doff,
    const float* __restrict__ wdef, const float* __restrict__ bdef,
    unsigned short* __restrict__ pcat_out,
    float* __restrict__ alignedf)
{
    __shared__ float wsm2[576];    // [k][c][o]
    const int L = blockIdx.x;
    const int xcd = L & 7;
    const int j = L >> 3;
    const int g = j & 7;
    const int r = (j >> 3) & 31;
    const int bi = j >> 8;
    const int h = xcd * 32 + r;
    const int px = threadIdx.x;

    for (int i = threadIdx.x; i < 576; i += 256) {
        int o = i & 7, c = (i >> 3) & 7, k = i >> 6;
        wsm2[i] = wdef[(size_t)g * 576 + o * 72 + c * 9 + k];
    }
    __syncthreads();

    const unsigned int* dp = (const unsigned int*)(
        doff + (((size_t)bi * HWsz) + (size_t)h * WW + px) * 144 + g * 18);
    unsigned int dw[9];
#pragma unroll
    for (int k = 0; k < 9; ++k) dw[k] = dp[k];

    float acc[8];
#pragma unroll
    for (int o = 0; o < 8; ++o) acc[o] = bdef[g * 8 + o];

    const unsigned short* rb = refg + (size_t)(bi * 8 + g) * HWsz * 8;

#pragma unroll
    for (int k = 0; k < 9; ++k) {
        float dy = bfhalf(dw[k], 0);
        float dx = bfhalf(dw[k], 1);
        float py = dy + (float)(h + k / 3 - 1);
        float pxs = dx + (float)(px + k % 3 - 1);
        float fy = floorf(py), fx = floorf(pxs);
        int y0 = (int)fy, x0i = (int)fx;
        float ly = py - fy, lx = pxs - fx;
        int y1 = y0 + 1, x1i = x0i + 1;
        bool vy0 = (y0 >= 0) & (y0 < HH), vy1 = (y1 >= 0) & (y1 < HH);
        bool vx0 = (x0i >= 0) & (x0i < WW), vx1 = (x1i >= 0) & (x1i < WW);
        int cy0 = min(max(y0, 0), HH - 1), cy1 = min(max(y1, 0), HH - 1);
        int cx0 = min(max(x0i, 0), WW - 1), cx1 = min(max(x1i, 0), WW - 1);
        float w00 = (1.f - ly) * (1.f - lx), w01 = (1.f - ly) * lx;
        float w10 = ly * (1.f - lx), w11 = ly * lx;
        if (!(vy0 && vx0)) w00 = 0.f;
        if (!(vy0 && vx1)) w01 = 0.f;
        if (!(vy1 && vx0)) w10 = 0.f;
        if (!(vy1 && vx1)) w11 = 0.f;

        uint4 q00 = *(const uint4*)(rb + ((size_t)cy0 * WW + cx0) * 8);
        uint4 q01 = *(const uint4*)(rb + ((size_t)cy0 * WW + cx1) * 8);
        uint4 q10 = *(const uint4*)(rb + ((size_t)cy1 * WW + cx0) * 8);
        uint4 q11 = *(const uint4*)(rb + ((size_t)cy1 * WW + cx1) * 8);
        union U { uint4 v; unsigned int a[4]; };
        U u00{q00}, u01{q01}, u10{q10}, u11{q11};

#pragma unroll
        for (int cw = 0; cw < 4; ++cw) {
#pragma unroll
            for (int hl = 0; hl < 2; ++hl) {
                int c = cw * 2 + hl;
                float sv = w00 * bfhalf(u00.a[cw], hl) + w01 * bfhalf(u01.a[cw], hl)
                         + w10 * bfhalf(u10.a[cw], hl) + w11 * bfhalf(u11.a[cw], hl);
                const float* wp = &wsm2[((k * 8) + c) * 8];
                float4v wlo = *(const float4v*)wp;
                float4v whi = *(const float4v*)(wp + 4);
                acc[0] += wlo[0] * sv; acc[1] += wlo[1] * sv;
                acc[2] += wlo[2] * sv; acc[3] += wlo[3] * sv;
                acc[4] += whi[0] * sv; acc[5] += whi[1] * sv;
                acc[6] += whi[2] * sv; acc[7] += whi[3] * sv;
            }
        }
    }

    float* af = alignedf + ((size_t)(bi * 64 + g * 8)) * HWsz + (size_t)h * WW + px;
#pragma unroll
    for (int o = 0; o < 8; ++o) af[(size_t)o * HWsz] = acc[o];

    unsigned short* po = pcat_out + (((size_t)bi * PD + (h + 1)) * PD + (px + 1)) * 128 + 64 + g * 8;
    uint4 pk;
    pk.x = f2bf(acc[0]) | ((unsigned)f2bf(acc[1]) << 16);
    pk.y = f2bf(acc[2]) | ((unsigned)f2bf(acc[3]) << 16);
    pk.z = f2bf(acc[4]) | ((unsigned)f2bf(acc[5]) << 16);
    pk.w = f2bf(acc[6]) | ((unsigned)f2bf(acc[7]) << 16);
    *(uint4*)po = pk;
}

// ---------------------------------------------------------------------------
extern "C" void kernel_launch(void* const* d_in, const int* in_sizes, int n_in,
                              void* d_out, int out_size, void* d_ws, size_t ws_size,
                              hipStream_t stream)
{
    const float* offset = (const float*)d_in[0];
    const float* ref    = (const float*)d_in[1];
    const float* w_off  = (const float*)d_in[2];
    const float* b_off  = (const float*)d_in[3];
    const float* w_def  = (const float*)d_in[4];
    const float* b_def  = (const float*)d_in[5];
    const float* w_r1   = (const float*)d_in[6];
    const float* b_r1   = (const float*)d_in[7];
    const float* w_r2   = (const float*)d_in[8];
    const float* b_r2   = (const float*)d_in[9];
    float* out = (float*)d_out;

    // workspace layout (ushort elems unless noted)
    unsigned short* p_off = (unsigned short*)d_ws;          // 2*258*258*64   = 8,520,192
    unsigned short* p_cat = p_off + (size_t)8520192;        // 2*258*258*128  = 17,040,384
    unsigned short* p_x1  = p_cat + (size_t)17040384;       // 8,520,192
    unsigned short* doff  = p_x1 + (size_t)8520192;         // 2*256*256*144  = 18,874,368
    unsigned short* refg  = doff + (size_t)18874368;        // 2*8*65536*8    = 8,388,608
    float* alignedf = (float*)(refg + (size_t)8388608);     // 8,388,608 floats
    short* wpk1  = (short*)(alignedf + (size_t)8388608);    // 110,592
    short* wpkr1 = wpk1 + 110592;                           // 73,728
    short* wpkr2 = wpkr1 + 73728;                           // 36,864
    // total ~150 MB

    // zero padded NHWC buffers (borders must be 0 every call)
    hipMemsetAsync(d_ws, 0, (size_t)(8520192 + 17040384 + 8520192) * 2, stream);

    pack_w<<<dim3((110592 + 255) / 256), 256, 0, stream>>>(w_off, wpk1, 144, 64, 110592);
    pack_w<<<dim3((73728 + 255) / 256), 256, 0, stream>>>(w_r1, wpkr1, 64, 128, 73728);
    pack_w<<<dim3((36864 + 255) / 256), 256, 0, stream>>>(w_r2, wpkr2, 64, 64, 36864);

    nchw_to_nhwc<64, false><<<dim3(256, 2), 256, 0, stream>>>(offset, p_off, nullptr);
    nchw_to_nhwc<128, true><<<dim3(256, 2), 256, 0, stream>>>(ref, p_cat, refg);

    // conv1: 64 -> 144 (padded 192, COTB=3)
    conv_mfma<64, 0, 3><<<dim3(2, 256, 6), 256, 0, stream>>>(
        p_off, wpk1, b_off, doff, nullptr, nullptr);

    // deform (4096 linear blocks, XCD row-band swizzle)
    deform_k3<<<dim3(4096), 256, 0, stream>>>(
        refg, doff, w_def, b_def, p_cat, alignedf);

    // r1: 128 -> 64, ReLU
    conv_mfma<128, 1, 1><<<dim3(2, 256, 2), 256, 0, stream>>>(
        p_cat, wpkr1, b_r1, p_x1, nullptr, nullptr);

    // r2: 64 -> 64, ReLU + residual
    conv_mfma<64, 2, 1><<<dim3(2, 256, 2), 256, 0, stream>>>(
        p_x1, wpkr2, b_r2, nullptr, out, alignedf);
}